// Round 17
// baseline (124.478 us; speedup 1.0000x reference)
//
#include <hip/hip_runtime.h>
#include <hip/hip_bf16.h>
#include <cstdint>

#define N 4096
#define L2E 1.44269504088896f

typedef __attribute__((ext_vector_type(2))) __fp16 fp16x2;
typedef __attribute__((ext_vector_type(2))) _Float16 h2f;
typedef __attribute__((ext_vector_type(8))) _Float16 half8;
typedef __attribute__((ext_vector_type(4))) float f32x4;
typedef __attribute__((ext_vector_type(16))) float f32x16;

__device__ __forceinline__ float elu_f(float x){ return x > 0.f ? x : __expf(x) - 1.f; }

// ---------------- adj -> transposed bitmask: bitsT[word][n] ----------------
__global__ __launch_bounds__(256) void mask_kernel(const int* __restrict__ adj,
                                                   unsigned long long* __restrict__ bitsT){
  int gw = (blockIdx.x * blockDim.x + threadIdx.x) >> 6;   // 0..16383
  int lane = threadIdx.x & 63;
  int n = gw >> 2;
  int q = gw & 3;
  const int4* src = (const int4*)(adj + (size_t)n * N + q * 1024);
  unsigned long long words[4];
  #pragma unroll
  for (int it = 0; it < 4; ++it){
    int4 v = src[it*64 + lane];
    unsigned long long nib = (unsigned long long)(
        (v.x != 0 ? 1u : 0u) | (v.y != 0 ? 2u : 0u) |
        (v.z != 0 ? 4u : 0u) | (v.w != 0 ? 8u : 0u));
    unsigned long long xw = nib << ((lane & 15) * 4);
    xw |= __shfl_xor(xw, 1);
    xw |= __shfl_xor(xw, 2);
    xw |= __shfl_xor(xw, 4);
    xw |= __shfl_xor(xw, 8);
    words[it] = xw;
  }
  if ((lane & 15) == 0){
    int k = lane >> 4;
    #pragma unroll
    for (int it = 0; it < 4; ++it){
      int w = q*16 + it*4 + k;
      bitsT[(size_t)w * N + n] = words[it];
    }
  }
}

// ------- fused layer-1 projection: Wh (fp16, transposed) + s/e vectors -----
__global__ __launch_bounds__(256) void wh1f_kernel(
    const float* __restrict__ x, const float* __restrict__ W, const float* __restrict__ a,
    ushort* __restrict__ WhT, float* __restrict__ sR,
    __fp16* __restrict__ e2p, __fp16* __restrict__ e2n){
  __shared__ float xs[16][128];
  int n0 = blockIdx.x * 16;
  int tid = threadIdx.x;
  {
    const float4* src = (const float4*)(x + (size_t)n0 * 128);
    float4* dst = (float4*)&xs[0][0];
    dst[tid] = src[tid];
    dst[tid + 256] = src[tid + 256];
  }
  __syncthreads();
  int h = tid >> 5;
  int g = tid & 31;
  int o = g * 2;
  const float* Wp = W + h * 8192 + o;
  float acc0[16], acc1[16];
  #pragma unroll
  for (int r = 0; r < 16; ++r){ acc0[r] = 0.f; acc1[r] = 0.f; }
  for (int f4 = 0; f4 < 32; ++f4){
    float2 wv0 = *(const float2*)(Wp + (f4*4+0)*64);
    float2 wv1 = *(const float2*)(Wp + (f4*4+1)*64);
    float2 wv2 = *(const float2*)(Wp + (f4*4+2)*64);
    float2 wv3 = *(const float2*)(Wp + (f4*4+3)*64);
    #pragma unroll
    for (int r = 0; r < 16; ++r){
      float4 xv = *(const float4*)&xs[r][f4*4];
      acc0[r] += xv.x*wv0.x; acc1[r] += xv.x*wv0.y;
      acc0[r] += xv.y*wv1.x; acc1[r] += xv.y*wv1.y;
      acc0[r] += xv.z*wv2.x; acc1[r] += xv.z*wv2.y;
      acc0[r] += xv.w*wv3.x; acc1[r] += xv.w*wv3.y;
    }
  }
  float a1o = a[h*128 + o],      a1o1 = a[h*128 + o + 1];
  float a2o = a[h*128 + 64 + o], a2o1 = a[h*128 + 64 + o + 1];
  float p1[16], p2[16];
  #pragma unroll
  for (int r = 0; r < 16; ++r){
    p1[r] = acc0[r]*a1o + acc1[r]*a1o1;
    p2[r] = acc0[r]*a2o + acc1[r]*a2o1;
  }
  #pragma unroll
  for (int s = 1; s <= 16; s <<= 1){
    #pragma unroll
    for (int r = 0; r < 16; ++r){
      p1[r] += __shfl_xor(p1[r], s);
      p2[r] += __shfl_xor(p2[r], s);
    }
  }
  if (g < 16){
    float f1 = 0.f, f2 = 0.f;
    #pragma unroll
    for (int r = 0; r < 16; ++r){
      f1 = (g == r) ? p1[r] : f1;
      f2 = (g == r) ? p2[r] : f2;
    }
    f1 *= L2E; f2 *= L2E;
    int base = h*N + n0 + g;
    sR[base]  = __builtin_amdgcn_exp2f(-0.8f*f1);
    e2p[base] = (__fp16)__builtin_amdgcn_exp2f(f2);
    e2n[base] = (__fp16)__builtin_amdgcn_exp2f(0.2f*f2);
  }
  union { fp16x2 d[8]; int4 q[2]; } pc0, pc1;
  #pragma unroll
  for (int r = 0; r < 8; ++r){
    pc0.d[r] = __builtin_amdgcn_cvt_pkrtz(acc0[2*r], acc0[2*r+1]);
    pc1.d[r] = __builtin_amdgcn_cvt_pkrtz(acc1[2*r], acc1[2*r+1]);
  }
  ushort* d0 = WhT + ((size_t)(h*64 + o))*N + n0;
  ushort* d1 = WhT + ((size_t)(h*64 + o + 1))*N + n0;
  *(int4*)d0 = pc0.q[0]; *(int4*)(d0+8) = pc0.q[1];
  *(int4*)d1 = pc1.q[0]; *(int4*)(d1+8) = pc1.q[1];
}

// ---------------- fin1: hmat(fp16) = elu(sum num / sum den) ----------------
__global__ __launch_bounds__(256) void fin1_kernel(const float* __restrict__ num,
                                                   const float* __restrict__ den,
                                                   ushort* __restrict__ hmat, int nch){
  int idx4 = blockIdx.x * 256 + threadIdx.x;   // over 8*N*64/4 = 524288 -> 2048 blocks
  int o4 = idx4 & 15;
  int hn = idx4 >> 4;
  int n = hn & (N - 1);
  int h = hn >> 12;
  const f32x4* num4 = (const f32x4*)num;
  f32x4 nu = {};
  float de = 0.f;
  for (int cc = 0; cc < nch; ++cc){
    nu += num4[(size_t)cc*(8*N*16) + (size_t)hn*16 + o4];
    de += den[(size_t)cc*(8*N) + hn];
  }
  float inv = 1.f / de;
  float v0 = elu_f(nu[0]*inv), v1 = elu_f(nu[1]*inv);
  float v2 = elu_f(nu[2]*inv), v3 = elu_f(nu[3]*inv);
  union { fp16x2 d[2]; uint2 q; } pc;
  pc.d[0] = __builtin_amdgcn_cvt_pkrtz(v0, v1);
  pc.d[1] = __builtin_amdgcn_cvt_pkrtz(v2, v3);
  *(uint2*)&hmat[(size_t)n*512 + h*64 + o4*4] = pc.q;
}

// ------- layer-2 projection from fp16 hmat: Wh2 (fp16,T) + s/e vectors -----
__global__ __launch_bounds__(256) void wh2f_kernel(
    const ushort* __restrict__ hmat,
    const float* __restrict__ W, const float* __restrict__ a,
    ushort* __restrict__ WhT, float* __restrict__ sR,
    __fp16* __restrict__ e2p, __fp16* __restrict__ e2n){
  __shared__ float hm[16][512];
  int n0 = blockIdx.x * 16;
  int tid = threadIdx.x;
  {
    const uint2* hsrc = (const uint2*)(hmat + (size_t)n0 * 512);
    #pragma unroll
    for (int e = 0; e < 8; ++e){
      int i = tid + e*256;
      union { uint2 q; __fp16 hf[4]; } u;
      u.q = hsrc[i];
      int r = i >> 7;
      int c = (i & 127) * 4;
      hm[r][c]   = (float)u.hf[0];
      hm[r][c+1] = (float)u.hf[1];
      hm[r][c+2] = (float)u.hf[2];
      hm[r][c+3] = (float)u.hf[3];
    }
  }
  __syncthreads();
  int o = tid & 63;
  int rq = tid >> 6;
  float acc[4] = {0.f,0.f,0.f,0.f};
  for (int f4 = 0; f4 < 128; ++f4){
    float w0 = W[(f4*4+0)*64 + o];
    float w1 = W[(f4*4+1)*64 + o];
    float w2 = W[(f4*4+2)*64 + o];
    float w3 = W[(f4*4+3)*64 + o];
    #pragma unroll
    for (int r = 0; r < 4; ++r){
      float4 xv = *(const float4*)&hm[rq*4 + r][f4*4];
      acc[r] += xv.x*w0 + xv.y*w1 + xv.z*w2 + xv.w*w3;
    }
  }
  float a1o = a[o], a2o = a[64 + o];
  float p1[4], p2[4];
  #pragma unroll
  for (int r = 0; r < 4; ++r){ p1[r] = acc[r]*a1o; p2[r] = acc[r]*a2o; }
  #pragma unroll
  for (int s = 1; s <= 32; s <<= 1){
    #pragma unroll
    for (int r = 0; r < 4; ++r){
      p1[r] += __shfl_xor(p1[r], s);
      p2[r] += __shfl_xor(p2[r], s);
    }
  }
  if (o < 4){
    float f1 = 0.f, f2 = 0.f;
    #pragma unroll
    for (int r = 0; r < 4; ++r){
      f1 = (o == r) ? p1[r] : f1;
      f2 = (o == r) ? p2[r] : f2;
    }
    f1 *= L2E; f2 *= L2E;
    int base = n0 + rq*4 + o;
    sR[base]  = __builtin_amdgcn_exp2f(-0.8f*f1);
    e2p[base] = (__fp16)__builtin_amdgcn_exp2f(f2);
    e2n[base] = (__fp16)__builtin_amdgcn_exp2f(0.2f*f2);
  }
  union { fp16x2 d[2]; uint2 q; } pc;
  pc.d[0] = __builtin_amdgcn_cvt_pkrtz(acc[0], acc[1]);
  pc.d[1] = __builtin_amdgcn_cvt_pkrtz(acc[2], acc[3]);
  ushort* d = WhT + (size_t)o*N + n0 + rq*4;
  *(uint2*)d = pc.q;
}

// ---------------- MFMA masked-softmax aggregation (32x32x16 fp16) ----------
// 256 thr (4 waves); 128 n x 64 o per block; wave owns 32 rows.
// e2p/e2n served from GLOBAL into registers (pipelined one tile ahead) —
// LDS holds only the B tile (double-buffered) + Mtbl.
__global__ __launch_bounds__(256) void attn_kernel(
    const ushort* __restrict__ WhT, const unsigned long long* __restrict__ bitsT,
    const float* __restrict__ sR,
    const __fp16* __restrict__ e2ph, const __fp16* __restrict__ e2nh,
    float* __restrict__ num, float* __restrict__ den, int Hn, int nchunks)
{
  __shared__ ushort Bt[2][4096];          // [64 o][64 m] fp16, swizzled 16B chunks
  __shared__ uint32_t Mtbl[256][4];       // bb8 -> 4 halfword-mask words
  const int bid  = blockIdx.x;
  const int t    = bid & 31;
  const int rest = bid >> 5;
  const int h    = rest % Hn;
  const int c    = rest / Hn;
  const int n0   = t << 7;                // 128 rows per block
  const int mlen = N / nchunks;
  const int m0b  = c * mlen;
  const int tid  = threadIdx.x;
  const int w    = tid >> 6;
  const int l    = tid & 63;
  const int r32  = l & 31;
  const int kg2  = l >> 5;
  const int n    = n0 + w*32 + r32;

  {
    int i = tid;
    Mtbl[i][0] = ((i&1)  ?0xFFFFu:0u) | ((i&2)  ?0xFFFF0000u:0u);
    Mtbl[i][1] = ((i&4)  ?0xFFFFu:0u) | ((i&8)  ?0xFFFF0000u:0u);
    Mtbl[i][2] = ((i&16) ?0xFFFFu:0u) | ((i&32) ?0xFFFF0000u:0u);
    Mtbl[i][3] = ((i&64) ?0xFFFFu:0u) | ((i&128)?0xFFFF0000u:0u);
  }

  const int hN = h * N;
  union { fp16x2 a; h2f b; } s2u;
  s2u.a = __builtin_amdgcn_cvt_pkrtz(sR[hN + n], sR[hN + n]);
  const h2f s2 = s2u.b;
  const h2f one2 = {(_Float16)1.f, (_Float16)1.f};
  const ushort* Wb = WhT + (size_t)h * 64 * N;
  const __fp16* epB = e2ph + hN + kg2*8;  // per-lane e slice base
  const __fp16* enB = e2nh + hN + kg2*8;

  const int so   = tid >> 3;              // 0..31
  const int slot = tid & 7;
  const int sc   = slot ^ (so & 7);

  f32x16 acc0 = {}, acc1 = {};
  float dA[4] = {0.f,0.f,0.f,0.f};

  // prologue: prefetch B tile 0 + e slices for tile 0 + adj word
  int4 sv0 = *(const int4*)(Wb + (size_t)so*N      + m0b + sc*8);
  int4 sv1 = *(const int4*)(Wb + (size_t)(so+32)*N + m0b + sc*8);
  int4 epq[4], enq[4];
  #pragma unroll
  for (int ks = 0; ks < 4; ++ks){
    epq[ks] = *(const int4*)(epB + m0b + ks*16);
    enq[ks] = *(const int4*)(enB + m0b + ks*16);
  }
  unsigned long long aw = bitsT[(size_t)(m0b >> 6)*N + n];

  #pragma unroll 1
  for (int mt = 0; mt < mlen; mt += 64){
    const int m0 = m0b + mt;
    const int buf = (mt >> 6) & 1;
    const uint32_t awlo = (uint32_t)aw, awhi = (uint32_t)(aw >> 32);
    *(int4*)&Bt[buf][so*64      + slot*8] = sv0;
    *(int4*)&Bt[buf][(so+32)*64 + slot*8] = sv1;
    if (mt + 64 < mlen){
      sv0 = *(const int4*)(Wb + (size_t)so*N      + m0 + 64 + sc*8);
      sv1 = *(const int4*)(Wb + (size_t)(so+32)*N + m0 + 64 + sc*8);
      aw = bitsT[(size_t)((m0 + 64) >> 6)*N + n];
    }
    __syncthreads();
    #pragma unroll
    for (int ks = 0; ks < 4; ++ks){
      union U16x8 { int4 q; half8 v; h2f p[4]; uint32_t u[4]; } ep, en, wv;
      ep.q = epq[ks];
      en.q = enq[ks];
      const int sh = (ks & 1)*16 + kg2*8;
      const uint32_t bb8 = (((ks < 2) ? awlo : awhi) >> sh) & 0xFFu;
      const uint32_t* mq = &Mtbl[bb8][0];
      #pragma unroll
      for (int p = 0; p < 4; ++p){
        h2f m = __builtin_elementwise_max(ep.p[p], en.p[p] * s2);
        uint32_t mu;
        __builtin_memcpy(&mu, &m, 4);
        mu &= mq[p];
        wv.u[p] = mu;
        h2f hm2;
        __builtin_memcpy(&hm2, &mu, 4);
        dA[p] = __builtin_amdgcn_fdot2(hm2, one2, dA[p], false);
      }
      const int ci = ks*2 + kg2;
      const int sw = (ci ^ (r32 & 7)) << 3;
      half8 B0 = *(const half8*)&Bt[buf][ r32      *64 + sw];
      half8 B1 = *(const half8*)&Bt[buf][(32 + r32)*64 + sw];
      acc0 = __builtin_amdgcn_mfma_f32_32x32x16_f16(wv.v, B0, acc0, 0, 0, 0);
      acc1 = __builtin_amdgcn_mfma_f32_32x32x16_f16(wv.v, B1, acc1, 0, 0, 0);
    }
    // reload e slices for next tile AFTER use (lands during next barrier/stage)
    if (mt + 64 < mlen){
      #pragma unroll
      for (int ks = 0; ks < 4; ++ks){
        epq[ks] = *(const int4*)(epB + m0 + 64 + ks*16);
        enq[ks] = *(const int4*)(enB + m0 + 64 + ks*16);
      }
    }
  }

  const size_t cb = (size_t)(c*Hn + h)*N;
  float* nb = num + (cb + n0 + w*32)*64;
  #pragma unroll
  for (int r = 0; r < 16; ++r){
    int row = (r & 3) + 8*(r >> 2) + 4*kg2;
    nb[(size_t)row*64 +      r32] = acc0[r];
    nb[(size_t)row*64 + 32 + r32] = acc1[r];
  }
  float dacc = (dA[0] + dA[1]) + (dA[2] + dA[3]);
  dacc += __shfl_xor(dacc, 32);
  if (l < 32)
    den[cb + n0 + w*32 + l] = dacc;
}

// ---------------- finalize layer 2: out = elu(sum num / sum den) -----------
__global__ __launch_bounds__(256) void fin2_kernel(const float* __restrict__ num,
                                                   const float* __restrict__ den,
                                                   float* __restrict__ out, int nch){
  int idx4 = blockIdx.x * 256 + threadIdx.x;    // over N*64/4 = 65536
  int n = idx4 >> 4;
  const f32x4* num4 = (const f32x4*)num;
  f32x4 s = {};
  float d = 0.f;
  for (int cc = 0; cc < nch; ++cc){
    s += num4[(size_t)cc*(N*16) + idx4];
    d += den[(size_t)cc*N + n];
  }
  float inv = 1.f / d;
  f32x4 r;
  #pragma unroll
  for (int j = 0; j < 4; ++j) r[j] = elu_f(s[j] * inv);
  *(f32x4*)(out + (size_t)idx4*4) = r;
}

extern "C" void kernel_launch(void* const* d_in, const int* in_sizes, int n_in,
                              void* d_out, int out_size, void* d_ws, size_t ws_size,
                              hipStream_t stream){
  const float* x       = (const float*)d_in[0];
  const int*   adj     = (const int*)d_in[1];
  const float* W_heads = (const float*)d_in[3];
  const float* a_heads = (const float*)d_in[4];
  const float* W_out   = (const float*)d_in[5];
  const float* a_out   = (const float*)d_in[6];
  float* out = (float*)d_out;
  char* ws = (char*)d_ws;

  const size_t MB = 1u << 20;
  const size_t KB = 1u << 10;
  unsigned long long* bitsT = (unsigned long long*)(ws);
  ushort* Wh2T = (ushort*)(ws + 2*MB);
  ushort* Wh1T = (ushort*)(ws + 2*MB + 512*KB);
  ushort* hmat = (ushort*)(ws + 2*MB + 512*KB);
  float*  sR1  = (float*)(ws + 6*MB + 512*KB);
  __fp16* e2p1 = (__fp16*)(ws + 6*MB + 640*KB);
  __fp16* e2n1 = (__fp16*)(ws + 6*MB + 704*KB);
  float*  sR2  = (float*)(ws + 6*MB + 768*KB);
  __fp16* e2p2 = (__fp16*)(ws + 6*MB + 784*KB);
  __fp16* e2n2 = (__fp16*)(ws + 6*MB + 792*KB);
  float*  den1 = (float*)(ws + 7*MB);
  float*  den2 = (float*)(ws + 8*MB);
  float*  num1 = (float*)(ws + 9*MB);
  float*  num2 = num1;

  const int nch1 = (ws_size >= (size_t)41*MB) ? 4 : 2;
  const int nch2 = 16;

  mask_kernel<<<4096, 256, 0, stream>>>(adj, bitsT);
  wh1f_kernel<<<256, 256, 0, stream>>>(x, W_heads, a_heads, Wh1T, sR1, e2p1, e2n1);
  attn_kernel<<<32*8*nch1, 256, 0, stream>>>(Wh1T, bitsT, sR1, e2p1, e2n1,
                                             num1, den1, 8, nch1);
  fin1_kernel<<<2048, 256, 0, stream>>>(num1, den1, hmat, nch1);
  wh2f_kernel<<<256, 256, 0, stream>>>(hmat, W_out, a_out, Wh2T, sR2, e2p2, e2n2);
  attn_kernel<<<32*1*nch2, 256, 0, stream>>>(Wh2T, bitsT, sR2, e2p2, e2n2,
                                             num2, den2, 1, nch2);
  fin2_kernel<<<256, 256, 0, stream>>>(num2, den2, out, nch2);
}

// Round 18
// 118.061 us; speedup vs baseline: 1.0544x; 1.0544x over previous
//
#include <hip/hip_runtime.h>
#include <hip/hip_bf16.h>
#include <cstdint>

#define N 4096
#define L2E 1.44269504088896f

typedef __attribute__((ext_vector_type(2))) __fp16 fp16x2;
typedef __attribute__((ext_vector_type(2))) _Float16 h2f;
typedef __attribute__((ext_vector_type(8))) _Float16 half8;
typedef __attribute__((ext_vector_type(4))) float f32x4;
typedef __attribute__((ext_vector_type(16))) float f32x16;

__device__ __forceinline__ float elu_f(float x){ return x > 0.f ? x : __expf(x) - 1.f; }

// ---------------- adj -> transposed bitmask: bitsT[word][n] ----------------
__global__ __launch_bounds__(256) void mask_kernel(const int* __restrict__ adj,
                                                   unsigned long long* __restrict__ bitsT){
  int gw = (blockIdx.x * blockDim.x + threadIdx.x) >> 6;   // 0..16383
  int lane = threadIdx.x & 63;
  int n = gw >> 2;
  int q = gw & 3;
  const int4* src = (const int4*)(adj + (size_t)n * N + q * 1024);
  unsigned long long words[4];
  #pragma unroll
  for (int it = 0; it < 4; ++it){
    int4 v = src[it*64 + lane];
    unsigned long long nib = (unsigned long long)(
        (v.x != 0 ? 1u : 0u) | (v.y != 0 ? 2u : 0u) |
        (v.z != 0 ? 4u : 0u) | (v.w != 0 ? 8u : 0u));
    unsigned long long xw = nib << ((lane & 15) * 4);
    xw |= __shfl_xor(xw, 1);
    xw |= __shfl_xor(xw, 2);
    xw |= __shfl_xor(xw, 4);
    xw |= __shfl_xor(xw, 8);
    words[it] = xw;
  }
  if ((lane & 15) == 0){
    int k = lane >> 4;
    #pragma unroll
    for (int it = 0; it < 4; ++it){
      int w = q*16 + it*4 + k;
      bitsT[(size_t)w * N + n] = words[it];
    }
  }
}

// ------- fused layer-1 projection: Wh (fp16, transposed) + s/e vectors -----
__global__ __launch_bounds__(256) void wh1f_kernel(
    const float* __restrict__ x, const float* __restrict__ W, const float* __restrict__ a,
    ushort* __restrict__ WhT, float* __restrict__ sR,
    __fp16* __restrict__ e2p, __fp16* __restrict__ e2n){
  __shared__ float xs[16][128];
  int n0 = blockIdx.x * 16;
  int tid = threadIdx.x;
  {
    const float4* src = (const float4*)(x + (size_t)n0 * 128);
    float4* dst = (float4*)&xs[0][0];
    dst[tid] = src[tid];
    dst[tid + 256] = src[tid + 256];
  }
  __syncthreads();
  int h = tid >> 5;
  int g = tid & 31;
  int o = g * 2;
  const float* Wp = W + h * 8192 + o;
  float acc0[16], acc1[16];
  #pragma unroll
  for (int r = 0; r < 16; ++r){ acc0[r] = 0.f; acc1[r] = 0.f; }
  for (int f4 = 0; f4 < 32; ++f4){
    float2 wv0 = *(const float2*)(Wp + (f4*4+0)*64);
    float2 wv1 = *(const float2*)(Wp + (f4*4+1)*64);
    float2 wv2 = *(const float2*)(Wp + (f4*4+2)*64);
    float2 wv3 = *(const float2*)(Wp + (f4*4+3)*64);
    #pragma unroll
    for (int r = 0; r < 16; ++r){
      float4 xv = *(const float4*)&xs[r][f4*4];
      acc0[r] += xv.x*wv0.x; acc1[r] += xv.x*wv0.y;
      acc0[r] += xv.y*wv1.x; acc1[r] += xv.y*wv1.y;
      acc0[r] += xv.z*wv2.x; acc1[r] += xv.z*wv2.y;
      acc0[r] += xv.w*wv3.x; acc1[r] += xv.w*wv3.y;
    }
  }
  float a1o = a[h*128 + o],      a1o1 = a[h*128 + o + 1];
  float a2o = a[h*128 + 64 + o], a2o1 = a[h*128 + 64 + o + 1];
  float p1[16], p2[16];
  #pragma unroll
  for (int r = 0; r < 16; ++r){
    p1[r] = acc0[r]*a1o + acc1[r]*a1o1;
    p2[r] = acc0[r]*a2o + acc1[r]*a2o1;
  }
  #pragma unroll
  for (int s = 1; s <= 16; s <<= 1){
    #pragma unroll
    for (int r = 0; r < 16; ++r){
      p1[r] += __shfl_xor(p1[r], s);
      p2[r] += __shfl_xor(p2[r], s);
    }
  }
  if (g < 16){
    float f1 = 0.f, f2 = 0.f;
    #pragma unroll
    for (int r = 0; r < 16; ++r){
      f1 = (g == r) ? p1[r] : f1;
      f2 = (g == r) ? p2[r] : f2;
    }
    f1 *= L2E; f2 *= L2E;
    int base = h*N + n0 + g;
    sR[base]  = __builtin_amdgcn_exp2f(-0.8f*f1);
    e2p[base] = (__fp16)__builtin_amdgcn_exp2f(f2);
    e2n[base] = (__fp16)__builtin_amdgcn_exp2f(0.2f*f2);
  }
  union { fp16x2 d[8]; int4 q[2]; } pc0, pc1;
  #pragma unroll
  for (int r = 0; r < 8; ++r){
    pc0.d[r] = __builtin_amdgcn_cvt_pkrtz(acc0[2*r], acc0[2*r+1]);
    pc1.d[r] = __builtin_amdgcn_cvt_pkrtz(acc1[2*r], acc1[2*r+1]);
  }
  ushort* d0 = WhT + ((size_t)(h*64 + o))*N + n0;
  ushort* d1 = WhT + ((size_t)(h*64 + o + 1))*N + n0;
  *(int4*)d0 = pc0.q[0]; *(int4*)(d0+8) = pc0.q[1];
  *(int4*)d1 = pc1.q[0]; *(int4*)(d1+8) = pc1.q[1];
}

// ---------------- fin1: hmat(fp16) = elu(sum num / sum den) ----------------
__global__ __launch_bounds__(256) void fin1_kernel(const float* __restrict__ num,
                                                   const float* __restrict__ den,
                                                   ushort* __restrict__ hmat, int nch){
  int idx4 = blockIdx.x * 256 + threadIdx.x;   // over 8*N*64/4 = 524288 -> 2048 blocks
  int o4 = idx4 & 15;
  int hn = idx4 >> 4;
  int n = hn & (N - 1);
  int h = hn >> 12;
  const f32x4* num4 = (const f32x4*)num;
  f32x4 nu = {};
  float de = 0.f;
  for (int cc = 0; cc < nch; ++cc){
    nu += num4[(size_t)cc*(8*N*16) + (size_t)hn*16 + o4];
    de += den[(size_t)cc*(8*N) + hn];
  }
  float inv = 1.f / de;
  float v0 = elu_f(nu[0]*inv), v1 = elu_f(nu[1]*inv);
  float v2 = elu_f(nu[2]*inv), v3 = elu_f(nu[3]*inv);
  union { fp16x2 d[2]; uint2 q; } pc;
  pc.d[0] = __builtin_amdgcn_cvt_pkrtz(v0, v1);
  pc.d[1] = __builtin_amdgcn_cvt_pkrtz(v2, v3);
  *(uint2*)&hmat[(size_t)n*512 + h*64 + o4*4] = pc.q;
}

// ------- layer-2 projection from fp16 hmat: Wh2 (fp16,T) + s/e vectors -----
__global__ __launch_bounds__(256) void wh2f_kernel(
    const ushort* __restrict__ hmat,
    const float* __restrict__ W, const float* __restrict__ a,
    ushort* __restrict__ WhT, float* __restrict__ sR,
    __fp16* __restrict__ e2p, __fp16* __restrict__ e2n){
  __shared__ float hm[16][512];
  int n0 = blockIdx.x * 16;
  int tid = threadIdx.x;
  {
    const uint2* hsrc = (const uint2*)(hmat + (size_t)n0 * 512);
    #pragma unroll
    for (int e = 0; e < 8; ++e){
      int i = tid + e*256;
      union { uint2 q; __fp16 hf[4]; } u;
      u.q = hsrc[i];
      int r = i >> 7;
      int c = (i & 127) * 4;
      hm[r][c]   = (float)u.hf[0];
      hm[r][c+1] = (float)u.hf[1];
      hm[r][c+2] = (float)u.hf[2];
      hm[r][c+3] = (float)u.hf[3];
    }
  }
  __syncthreads();
  int o = tid & 63;
  int rq = tid >> 6;
  float acc[4] = {0.f,0.f,0.f,0.f};
  for (int f4 = 0; f4 < 128; ++f4){
    float w0 = W[(f4*4+0)*64 + o];
    float w1 = W[(f4*4+1)*64 + o];
    float w2 = W[(f4*4+2)*64 + o];
    float w3 = W[(f4*4+3)*64 + o];
    #pragma unroll
    for (int r = 0; r < 4; ++r){
      float4 xv = *(const float4*)&hm[rq*4 + r][f4*4];
      acc[r] += xv.x*w0 + xv.y*w1 + xv.z*w2 + xv.w*w3;
    }
  }
  float a1o = a[o], a2o = a[64 + o];
  float p1[4], p2[4];
  #pragma unroll
  for (int r = 0; r < 4; ++r){ p1[r] = acc[r]*a1o; p2[r] = acc[r]*a2o; }
  #pragma unroll
  for (int s = 1; s <= 32; s <<= 1){
    #pragma unroll
    for (int r = 0; r < 4; ++r){
      p1[r] += __shfl_xor(p1[r], s);
      p2[r] += __shfl_xor(p2[r], s);
    }
  }
  if (o < 4){
    float f1 = 0.f, f2 = 0.f;
    #pragma unroll
    for (int r = 0; r < 4; ++r){
      f1 = (o == r) ? p1[r] : f1;
      f2 = (o == r) ? p2[r] : f2;
    }
    f1 *= L2E; f2 *= L2E;
    int base = n0 + rq*4 + o;
    sR[base]  = __builtin_amdgcn_exp2f(-0.8f*f1);
    e2p[base] = (__fp16)__builtin_amdgcn_exp2f(f2);
    e2n[base] = (__fp16)__builtin_amdgcn_exp2f(0.2f*f2);
  }
  union { fp16x2 d[2]; uint2 q; } pc;
  pc.d[0] = __builtin_amdgcn_cvt_pkrtz(acc[0], acc[1]);
  pc.d[1] = __builtin_amdgcn_cvt_pkrtz(acc[2], acc[3]);
  ushort* d = WhT + (size_t)o*N + n0 + rq*4;
  *(uint2*)d = pc.q;
}

// ---------------- MFMA masked-softmax aggregation (32x32x16 fp16) ----------
// 256 thr (4 waves); 128 n x 64 o per block; wave owns 32 rows.
// Packed-fp16 A-build (pk_mul+pk_max+and via Mtbl), 4-way fdot2 den,
// double-buffered Bt/Et with register prefetch, ONE barrier per tile.
__global__ __launch_bounds__(256) void attn_kernel(
    const ushort* __restrict__ WhT, const unsigned long long* __restrict__ bitsT,
    const float* __restrict__ sR,
    const __fp16* __restrict__ e2ph, const __fp16* __restrict__ e2nh,
    float* __restrict__ num, float* __restrict__ den, int Hn, int nchunks)
{
  __shared__ ushort Bt[2][4096];          // [64 o][64 m] fp16, swizzled 16B chunks
  __shared__ __fp16 EtP[2][64], EtN[2][64];
  __shared__ uint32_t Mtbl[256][4];       // bb8 -> 4 halfword-mask words
  const int bid  = blockIdx.x;
  const int t    = bid & 31;
  const int rest = bid >> 5;
  const int h    = rest % Hn;
  const int c    = rest / Hn;
  const int n0   = t << 7;                // 128 rows per block
  const int mlen = N / nchunks;
  const int m0b  = c * mlen;
  const int tid  = threadIdx.x;
  const int w    = tid >> 6;
  const int l    = tid & 63;
  const int r32  = l & 31;
  const int kg2  = l >> 5;
  const int n    = n0 + w*32 + r32;

  {
    int i = tid;
    Mtbl[i][0] = ((i&1)  ?0xFFFFu:0u) | ((i&2)  ?0xFFFF0000u:0u);
    Mtbl[i][1] = ((i&4)  ?0xFFFFu:0u) | ((i&8)  ?0xFFFF0000u:0u);
    Mtbl[i][2] = ((i&16) ?0xFFFFu:0u) | ((i&32) ?0xFFFF0000u:0u);
    Mtbl[i][3] = ((i&64) ?0xFFFFu:0u) | ((i&128)?0xFFFF0000u:0u);
  }

  const int hN = h * N;
  union { fp16x2 a; h2f b; } s2u;
  s2u.a = __builtin_amdgcn_cvt_pkrtz(sR[hN + n], sR[hN + n]);
  const h2f s2 = s2u.b;
  const h2f one2 = {(_Float16)1.f, (_Float16)1.f};
  const ushort* Wb = WhT + (size_t)h * 64 * N;

  const int so   = tid >> 3;              // 0..31
  const int slot = tid & 7;
  const int sc   = slot ^ (so & 7);
  const __fp16* evsrc = (((tid & 8) ? e2nh : e2ph) + hN) + ((tid & 7) << 3);

  f32x16 acc0 = {}, acc1 = {};
  float dA[4] = {0.f,0.f,0.f,0.f};

  int4 sv0 = *(const int4*)(Wb + (size_t)so*N      + m0b + sc*8);
  int4 sv1 = *(const int4*)(Wb + (size_t)(so+32)*N + m0b + sc*8);
  int4 evq = {};
  if (tid < 16) evq = *(const int4*)(evsrc + m0b);
  unsigned long long aw = bitsT[(size_t)(m0b >> 6)*N + n];

  #pragma unroll 1
  for (int mt = 0; mt < mlen; mt += 64){
    const int m0 = m0b + mt;
    const int buf = (mt >> 6) & 1;
    const uint32_t awlo = (uint32_t)aw, awhi = (uint32_t)(aw >> 32);
    *(int4*)&Bt[buf][so*64      + slot*8] = sv0;
    *(int4*)&Bt[buf][(so+32)*64 + slot*8] = sv1;
    if (tid < 16)
      *(int4*)(((tid & 8) ? &EtN[buf][0] : &EtP[buf][0]) + ((tid & 7) << 3)) = evq;
    if (mt + 64 < mlen){
      sv0 = *(const int4*)(Wb + (size_t)so*N      + m0 + 64 + sc*8);
      sv1 = *(const int4*)(Wb + (size_t)(so+32)*N + m0 + 64 + sc*8);
      if (tid < 16) evq = *(const int4*)(evsrc + m0 + 64);
      aw = bitsT[(size_t)((m0 + 64) >> 6)*N + n];
    }
    __syncthreads();
    #pragma unroll
    for (int ks = 0; ks < 4; ++ks){
      const int mo = ks*16 + kg2*8;
      union U16x8 { half8 v; h2f p[4]; uint32_t u[4]; } ep, en, wv;
      ep.v = *(const half8*)&EtP[buf][mo];
      en.v = *(const half8*)&EtN[buf][mo];
      const int sh = (ks & 1)*16 + kg2*8;
      const uint32_t bb8 = (((ks < 2) ? awlo : awhi) >> sh) & 0xFFu;
      const uint32_t* mq = &Mtbl[bb8][0];
      #pragma unroll
      for (int p = 0; p < 4; ++p){
        h2f m = __builtin_elementwise_max(ep.p[p], en.p[p] * s2);
        uint32_t mu;
        __builtin_memcpy(&mu, &m, 4);
        mu &= mq[p];
        wv.u[p] = mu;
        h2f hm2;
        __builtin_memcpy(&hm2, &mu, 4);
        dA[p] = __builtin_amdgcn_fdot2(hm2, one2, dA[p], false);
      }
      const int ci = ks*2 + kg2;
      const int sw = (ci ^ (r32 & 7)) << 3;
      half8 B0 = *(const half8*)&Bt[buf][ r32      *64 + sw];
      half8 B1 = *(const half8*)&Bt[buf][(32 + r32)*64 + sw];
      acc0 = __builtin_amdgcn_mfma_f32_32x32x16_f16(wv.v, B0, acc0, 0, 0, 0);
      acc1 = __builtin_amdgcn_mfma_f32_32x32x16_f16(wv.v, B1, acc1, 0, 0, 0);
    }
  }

  const size_t cb = (size_t)(c*Hn + h)*N;
  float* nb = num + (cb + n0 + w*32)*64;
  #pragma unroll
  for (int r = 0; r < 16; ++r){
    int row = (r & 3) + 8*(r >> 2) + 4*kg2;
    nb[(size_t)row*64 +      r32] = acc0[r];
    nb[(size_t)row*64 + 32 + r32] = acc1[r];
  }
  float dacc = (dA[0] + dA[1]) + (dA[2] + dA[3]);
  dacc += __shfl_xor(dacc, 32);
  if (l < 32)
    den[cb + n0 + w*32 + l] = dacc;
}

// ---------------- finalize layer 2: out = elu(sum num / sum den) -----------
__global__ __launch_bounds__(256) void fin2_kernel(const float* __restrict__ num,
                                                   const float* __restrict__ den,
                                                   float* __restrict__ out, int nch){
  int idx4 = blockIdx.x * 256 + threadIdx.x;    // over N*64/4 = 65536
  int n = idx4 >> 4;
  const f32x4* num4 = (const f32x4*)num;
  f32x4 s = {};
  float d = 0.f;
  for (int cc = 0; cc < nch; ++cc){
    s += num4[(size_t)cc*(N*16) + idx4];
    d += den[(size_t)cc*N + n];
  }
  float inv = 1.f / d;
  f32x4 r;
  #pragma unroll
  for (int j = 0; j < 4; ++j) r[j] = elu_f(s[j] * inv);
  *(f32x4*)(out + (size_t)idx4*4) = r;
}

extern "C" void kernel_launch(void* const* d_in, const int* in_sizes, int n_in,
                              void* d_out, int out_size, void* d_ws, size_t ws_size,
                              hipStream_t stream){
  const float* x       = (const float*)d_in[0];
  const int*   adj     = (const int*)d_in[1];
  const float* W_heads = (const float*)d_in[3];
  const float* a_heads = (const float*)d_in[4];
  const float* W_out   = (const float*)d_in[5];
  const float* a_out   = (const float*)d_in[6];
  float* out = (float*)d_out;
  char* ws = (char*)d_ws;

  const size_t MB = 1u << 20;
  const size_t KB = 1u << 10;
  unsigned long long* bitsT = (unsigned long long*)(ws);
  ushort* Wh2T = (ushort*)(ws + 2*MB);
  ushort* Wh1T = (ushort*)(ws + 2*MB + 512*KB);
  ushort* hmat = (ushort*)(ws + 2*MB + 512*KB);
  float*  sR1  = (float*)(ws + 6*MB + 512*KB);
  __fp16* e2p1 = (__fp16*)(ws + 6*MB + 640*KB);
  __fp16* e2n1 = (__fp16*)(ws + 6*MB + 704*KB);
  float*  sR2  = (float*)(ws + 6*MB + 768*KB);
  __fp16* e2p2 = (__fp16*)(ws + 6*MB + 784*KB);
  __fp16* e2n2 = (__fp16*)(ws + 6*MB + 792*KB);
  float*  den1 = (float*)(ws + 7*MB);
  float*  den2 = (float*)(ws + 8*MB);
  float*  num1 = (float*)(ws + 9*MB);
  float*  num2 = num1;

  const int nch1 = (ws_size >= (size_t)41*MB) ? 4 : 2;
  const int nch2 = 16;

  mask_kernel<<<4096, 256, 0, stream>>>(adj, bitsT);
  wh1f_kernel<<<256, 256, 0, stream>>>(x, W_heads, a_heads, Wh1T, sR1, e2p1, e2n1);
  attn_kernel<<<32*8*nch1, 256, 0, stream>>>(Wh1T, bitsT, sR1, e2p1, e2n1,
                                             num1, den1, 8, nch1);
  fin1_kernel<<<2048, 256, 0, stream>>>(num1, den1, hmat, nch1);
  wh2f_kernel<<<256, 256, 0, stream>>>(hmat, W_out, a_out, Wh2T, sR2, e2p2, e2n2);
  attn_kernel<<<32*1*nch2, 256, 0, stream>>>(Wh2T, bitsT, sR2, e2p2, e2n2,
                                             num2, den2, 1, nch2);
  fin2_kernel<<<256, 256, 0, stream>>>(num2, den2, out, nch2);
}

// Round 19
// 107.181 us; speedup vs baseline: 1.1614x; 1.1015x over previous
//
#include <hip/hip_runtime.h>
#include <hip/hip_bf16.h>
#include <cstdint>

#define N 4096
#define L2E 1.44269504088896f

typedef __attribute__((ext_vector_type(2))) __fp16 fp16x2;
typedef __attribute__((ext_vector_type(2))) _Float16 h2f;
typedef __attribute__((ext_vector_type(8))) _Float16 half8;
typedef __attribute__((ext_vector_type(4))) float f32x4;
typedef __attribute__((ext_vector_type(16))) float f32x16;

__device__ __forceinline__ float elu_f(float x){ return x > 0.f ? x : __expf(x) - 1.f; }

// ---------------- adj -> transposed bitmask: bitsT[word][n] ----------------
__global__ __launch_bounds__(256) void mask_kernel(const int* __restrict__ adj,
                                                   unsigned long long* __restrict__ bitsT){
  int gw = (blockIdx.x * blockDim.x + threadIdx.x) >> 6;   // 0..16383
  int lane = threadIdx.x & 63;
  int n = gw >> 2;
  int q = gw & 3;
  const int4* src = (const int4*)(adj + (size_t)n * N + q * 1024);
  unsigned long long words[4];
  #pragma unroll
  for (int it = 0; it < 4; ++it){
    int4 v = src[it*64 + lane];
    unsigned long long nib = (unsigned long long)(
        (v.x != 0 ? 1u : 0u) | (v.y != 0 ? 2u : 0u) |
        (v.z != 0 ? 4u : 0u) | (v.w != 0 ? 8u : 0u));
    unsigned long long xw = nib << ((lane & 15) * 4);
    xw |= __shfl_xor(xw, 1);
    xw |= __shfl_xor(xw, 2);
    xw |= __shfl_xor(xw, 4);
    xw |= __shfl_xor(xw, 8);
    words[it] = xw;
  }
  if ((lane & 15) == 0){
    int k = lane >> 4;
    #pragma unroll
    for (int it = 0; it < 4; ++it){
      int w = q*16 + it*4 + k;
      bitsT[(size_t)w * N + n] = words[it];
    }
  }
}

// ------- fused layer-1 projection (8-row blocks): WhT + s/e vectors --------
__global__ __launch_bounds__(256) void wh1f_kernel(
    const float* __restrict__ x, const float* __restrict__ W, const float* __restrict__ a,
    ushort* __restrict__ WhT, float* __restrict__ sR,
    __fp16* __restrict__ e2p, __fp16* __restrict__ e2n){
  __shared__ float xs[8][128];
  int n0 = blockIdx.x * 8;
  int tid = threadIdx.x;
  {
    const float4* src = (const float4*)(x + (size_t)n0 * 128);
    float4* dst = (float4*)&xs[0][0];
    dst[tid] = src[tid];                 // 8x128 f32 = 256 float4
  }
  __syncthreads();
  int h = tid >> 5;
  int g = tid & 31;
  int o = g * 2;
  const float* Wp = W + h * 8192 + o;
  float acc0[8], acc1[8];
  #pragma unroll
  for (int r = 0; r < 8; ++r){ acc0[r] = 0.f; acc1[r] = 0.f; }
  for (int f4 = 0; f4 < 32; ++f4){
    float2 wv0 = *(const float2*)(Wp + (f4*4+0)*64);
    float2 wv1 = *(const float2*)(Wp + (f4*4+1)*64);
    float2 wv2 = *(const float2*)(Wp + (f4*4+2)*64);
    float2 wv3 = *(const float2*)(Wp + (f4*4+3)*64);
    #pragma unroll
    for (int r = 0; r < 8; ++r){
      float4 xv = *(const float4*)&xs[r][f4*4];
      acc0[r] += xv.x*wv0.x; acc1[r] += xv.x*wv0.y;
      acc0[r] += xv.y*wv1.x; acc1[r] += xv.y*wv1.y;
      acc0[r] += xv.z*wv2.x; acc1[r] += xv.z*wv2.y;
      acc0[r] += xv.w*wv3.x; acc1[r] += xv.w*wv3.y;
    }
  }
  float a1o = a[h*128 + o],      a1o1 = a[h*128 + o + 1];
  float a2o = a[h*128 + 64 + o], a2o1 = a[h*128 + 64 + o + 1];
  float p1[8], p2[8];
  #pragma unroll
  for (int r = 0; r < 8; ++r){
    p1[r] = acc0[r]*a1o + acc1[r]*a1o1;
    p2[r] = acc0[r]*a2o + acc1[r]*a2o1;
  }
  #pragma unroll
  for (int s = 1; s <= 16; s <<= 1){
    #pragma unroll
    for (int r = 0; r < 8; ++r){
      p1[r] += __shfl_xor(p1[r], s);
      p2[r] += __shfl_xor(p2[r], s);
    }
  }
  if (g < 8){
    float f1 = 0.f, f2 = 0.f;
    #pragma unroll
    for (int r = 0; r < 8; ++r){
      f1 = (g == r) ? p1[r] : f1;
      f2 = (g == r) ? p2[r] : f2;
    }
    f1 *= L2E; f2 *= L2E;
    int base = h*N + n0 + g;
    sR[base]  = __builtin_amdgcn_exp2f(-0.8f*f1);
    e2p[base] = (__fp16)__builtin_amdgcn_exp2f(f2);
    e2n[base] = (__fp16)__builtin_amdgcn_exp2f(0.2f*f2);
  }
  union { fp16x2 d[4]; int4 q; } pc0, pc1;
  #pragma unroll
  for (int r = 0; r < 4; ++r){
    pc0.d[r] = __builtin_amdgcn_cvt_pkrtz(acc0[2*r], acc0[2*r+1]);
    pc1.d[r] = __builtin_amdgcn_cvt_pkrtz(acc1[2*r], acc1[2*r+1]);
  }
  ushort* d0 = WhT + ((size_t)(h*64 + o))*N + n0;
  ushort* d1 = WhT + ((size_t)(h*64 + o + 1))*N + n0;
  *(int4*)d0 = pc0.q;
  *(int4*)d1 = pc1.q;
}

// ---------------- fin1: hmat(fp16) = elu(sum num / sum den) ----------------
__global__ __launch_bounds__(256) void fin1_kernel(const float* __restrict__ num,
                                                   const float* __restrict__ den,
                                                   ushort* __restrict__ hmat, int nch){
  int idx4 = blockIdx.x * 256 + threadIdx.x;   // over 8*N*64/4 = 524288 -> 2048 blocks
  int o4 = idx4 & 15;
  int hn = idx4 >> 4;
  int n = hn & (N - 1);
  int h = hn >> 12;
  const f32x4* num4 = (const f32x4*)num;
  f32x4 nu = {};
  float de = 0.f;
  for (int cc = 0; cc < nch; ++cc){
    nu += num4[(size_t)cc*(8*N*16) + (size_t)hn*16 + o4];
    de += den[(size_t)cc*(8*N) + hn];
  }
  float inv = 1.f / de;
  float v0 = elu_f(nu[0]*inv), v1 = elu_f(nu[1]*inv);
  float v2 = elu_f(nu[2]*inv), v3 = elu_f(nu[3]*inv);
  union { fp16x2 d[2]; uint2 q; } pc;
  pc.d[0] = __builtin_amdgcn_cvt_pkrtz(v0, v1);
  pc.d[1] = __builtin_amdgcn_cvt_pkrtz(v2, v3);
  *(uint2*)&hmat[(size_t)n*512 + h*64 + o4*4] = pc.q;
}

// ------- layer-2 projection (8-row blocks) from fp16 hmat ------------------
__global__ __launch_bounds__(256) void wh2f_kernel(
    const ushort* __restrict__ hmat,
    const float* __restrict__ W, const float* __restrict__ a,
    ushort* __restrict__ WhT, float* __restrict__ sR,
    __fp16* __restrict__ e2p, __fp16* __restrict__ e2n){
  __shared__ float hm[8][512];
  int n0 = blockIdx.x * 8;
  int tid = threadIdx.x;
  {
    const uint2* hsrc = (const uint2*)(hmat + (size_t)n0 * 512);   // 1024 uint2
    #pragma unroll
    for (int e = 0; e < 4; ++e){
      int i = tid + e*256;
      union { uint2 q; __fp16 hf[4]; } u;
      u.q = hsrc[i];
      int r = i >> 7;
      int c = (i & 127) * 4;
      hm[r][c]   = (float)u.hf[0];
      hm[r][c+1] = (float)u.hf[1];
      hm[r][c+2] = (float)u.hf[2];
      hm[r][c+3] = (float)u.hf[3];
    }
  }
  __syncthreads();
  int o = tid & 63;
  int rq = tid >> 6;           // 4 groups x 2 rows
  float acc[2] = {0.f, 0.f};
  for (int f4 = 0; f4 < 128; ++f4){
    float w0 = W[(f4*4+0)*64 + o];
    float w1 = W[(f4*4+1)*64 + o];
    float w2 = W[(f4*4+2)*64 + o];
    float w3 = W[(f4*4+3)*64 + o];
    #pragma unroll
    for (int r = 0; r < 2; ++r){
      float4 xv = *(const float4*)&hm[rq*2 + r][f4*4];
      acc[r] += xv.x*w0 + xv.y*w1 + xv.z*w2 + xv.w*w3;
    }
  }
  float a1o = a[o], a2o = a[64 + o];
  float p1[2], p2[2];
  #pragma unroll
  for (int r = 0; r < 2; ++r){ p1[r] = acc[r]*a1o; p2[r] = acc[r]*a2o; }
  #pragma unroll
  for (int s = 1; s <= 32; s <<= 1){
    #pragma unroll
    for (int r = 0; r < 2; ++r){
      p1[r] += __shfl_xor(p1[r], s);
      p2[r] += __shfl_xor(p2[r], s);
    }
  }
  if (o < 2){
    float f1 = 0.f, f2 = 0.f;
    #pragma unroll
    for (int r = 0; r < 2; ++r){
      f1 = (o == r) ? p1[r] : f1;
      f2 = (o == r) ? p2[r] : f2;
    }
    f1 *= L2E; f2 *= L2E;
    int base = n0 + rq*2 + o;
    sR[base]  = __builtin_amdgcn_exp2f(-0.8f*f1);
    e2p[base] = (__fp16)__builtin_amdgcn_exp2f(f2);
    e2n[base] = (__fp16)__builtin_amdgcn_exp2f(0.2f*f2);
  }
  union { fp16x2 d; uint32_t q; } pc;
  pc.d = __builtin_amdgcn_cvt_pkrtz(acc[0], acc[1]);
  ushort* d = WhT + (size_t)o*N + n0 + rq*2;
  *(uint32_t*)d = pc.q;
}

// ---------------- MFMA masked-softmax aggregation (32x32x16 fp16) ----------
// 256 thr (4 waves); 128 n x 64 o per block; wave owns 32 rows.
// Packed-fp16 A-build (pk_mul+pk_max+and via Mtbl), 4-way fdot2 den,
// double-buffered Bt/Et with register prefetch, ONE barrier per tile.
__global__ __launch_bounds__(256) void attn_kernel(
    const ushort* __restrict__ WhT, const unsigned long long* __restrict__ bitsT,
    const float* __restrict__ sR,
    const __fp16* __restrict__ e2ph, const __fp16* __restrict__ e2nh,
    float* __restrict__ num, float* __restrict__ den, int Hn, int nchunks)
{
  __shared__ ushort Bt[2][4096];          // [64 o][64 m] fp16, swizzled 16B chunks
  __shared__ __fp16 EtP[2][64], EtN[2][64];
  __shared__ uint32_t Mtbl[256][4];       // bb8 -> 4 halfword-mask words
  const int bid  = blockIdx.x;
  const int t    = bid & 31;
  const int rest = bid >> 5;
  const int h    = rest % Hn;
  const int c    = rest / Hn;
  const int n0   = t << 7;                // 128 rows per block
  const int mlen = N / nchunks;
  const int m0b  = c * mlen;
  const int tid  = threadIdx.x;
  const int w    = tid >> 6;
  const int l    = tid & 63;
  const int r32  = l & 31;
  const int kg2  = l >> 5;
  const int n    = n0 + w*32 + r32;

  {
    int i = tid;
    Mtbl[i][0] = ((i&1)  ?0xFFFFu:0u) | ((i&2)  ?0xFFFF0000u:0u);
    Mtbl[i][1] = ((i&4)  ?0xFFFFu:0u) | ((i&8)  ?0xFFFF0000u:0u);
    Mtbl[i][2] = ((i&16) ?0xFFFFu:0u) | ((i&32) ?0xFFFF0000u:0u);
    Mtbl[i][3] = ((i&64) ?0xFFFFu:0u) | ((i&128)?0xFFFF0000u:0u);
  }

  const int hN = h * N;
  union { fp16x2 a; h2f b; } s2u;
  s2u.a = __builtin_amdgcn_cvt_pkrtz(sR[hN + n], sR[hN + n]);
  const h2f s2 = s2u.b;
  const h2f one2 = {(_Float16)1.f, (_Float16)1.f};
  const ushort* Wb = WhT + (size_t)h * 64 * N;

  const int so   = tid >> 3;              // 0..31
  const int slot = tid & 7;
  const int sc   = slot ^ (so & 7);
  const __fp16* evsrc = (((tid & 8) ? e2nh : e2ph) + hN) + ((tid & 7) << 3);

  f32x16 acc0 = {}, acc1 = {};
  float dA[4] = {0.f,0.f,0.f,0.f};

  int4 sv0 = *(const int4*)(Wb + (size_t)so*N      + m0b + sc*8);
  int4 sv1 = *(const int4*)(Wb + (size_t)(so+32)*N + m0b + sc*8);
  int4 evq = {};
  if (tid < 16) evq = *(const int4*)(evsrc + m0b);
  unsigned long long aw = bitsT[(size_t)(m0b >> 6)*N + n];

  #pragma unroll 1
  for (int mt = 0; mt < mlen; mt += 64){
    const int m0 = m0b + mt;
    const int buf = (mt >> 6) & 1;
    const uint32_t awlo = (uint32_t)aw, awhi = (uint32_t)(aw >> 32);
    *(int4*)&Bt[buf][so*64      + slot*8] = sv0;
    *(int4*)&Bt[buf][(so+32)*64 + slot*8] = sv1;
    if (tid < 16)
      *(int4*)(((tid & 8) ? &EtN[buf][0] : &EtP[buf][0]) + ((tid & 7) << 3)) = evq;
    if (mt + 64 < mlen){
      sv0 = *(const int4*)(Wb + (size_t)so*N      + m0 + 64 + sc*8);
      sv1 = *(const int4*)(Wb + (size_t)(so+32)*N + m0 + 64 + sc*8);
      if (tid < 16) evq = *(const int4*)(evsrc + m0 + 64);
      aw = bitsT[(size_t)((m0 + 64) >> 6)*N + n];
    }
    __syncthreads();
    #pragma unroll
    for (int ks = 0; ks < 4; ++ks){
      const int mo = ks*16 + kg2*8;
      union U16x8 { half8 v; h2f p[4]; uint32_t u[4]; } ep, en, wv;
      ep.v = *(const half8*)&EtP[buf][mo];
      en.v = *(const half8*)&EtN[buf][mo];
      const int sh = (ks & 1)*16 + kg2*8;
      const uint32_t bb8 = (((ks < 2) ? awlo : awhi) >> sh) & 0xFFu;
      const uint32_t* mq = &Mtbl[bb8][0];
      #pragma unroll
      for (int p = 0; p < 4; ++p){
        h2f m = __builtin_elementwise_max(ep.p[p], en.p[p] * s2);
        uint32_t mu;
        __builtin_memcpy(&mu, &m, 4);
        mu &= mq[p];
        wv.u[p] = mu;
        h2f hm2;
        __builtin_memcpy(&hm2, &mu, 4);
        dA[p] = __builtin_amdgcn_fdot2(hm2, one2, dA[p], false);
      }
      const int ci = ks*2 + kg2;
      const int sw = (ci ^ (r32 & 7)) << 3;
      half8 B0 = *(const half8*)&Bt[buf][ r32      *64 + sw];
      half8 B1 = *(const half8*)&Bt[buf][(32 + r32)*64 + sw];
      acc0 = __builtin_amdgcn_mfma_f32_32x32x16_f16(wv.v, B0, acc0, 0, 0, 0);
      acc1 = __builtin_amdgcn_mfma_f32_32x32x16_f16(wv.v, B1, acc1, 0, 0, 0);
    }
  }

  const size_t cb = (size_t)(c*Hn + h)*N;
  float* nb = num + (cb + n0 + w*32)*64;
  #pragma unroll
  for (int r = 0; r < 16; ++r){
    int row = (r & 3) + 8*(r >> 2) + 4*kg2;
    nb[(size_t)row*64 +      r32] = acc0[r];
    nb[(size_t)row*64 + 32 + r32] = acc1[r];
  }
  float dacc = (dA[0] + dA[1]) + (dA[2] + dA[3]);
  dacc += __shfl_xor(dacc, 32);
  if (l < 32)
    den[cb + n0 + w*32 + l] = dacc;
}

// ---------------- finalize layer 2: out = elu(sum num / sum den) -----------
__global__ __launch_bounds__(256) void fin2_kernel(const float* __restrict__ num,
                                                   const float* __restrict__ den,
                                                   float* __restrict__ out, int nch){
  int idx4 = blockIdx.x * 256 + threadIdx.x;    // over N*64/4 = 65536
  int n = idx4 >> 4;
  const f32x4* num4 = (const f32x4*)num;
  f32x4 s = {};
  float d = 0.f;
  for (int cc = 0; cc < nch; ++cc){
    s += num4[(size_t)cc*(N*16) + idx4];
    d += den[(size_t)cc*N + n];
  }
  float inv = 1.f / d;
  f32x4 r;
  #pragma unroll
  for (int j = 0; j < 4; ++j) r[j] = elu_f(s[j] * inv);
  *(f32x4*)(out + (size_t)idx4*4) = r;
}

extern "C" void kernel_launch(void* const* d_in, const int* in_sizes, int n_in,
                              void* d_out, int out_size, void* d_ws, size_t ws_size,
                              hipStream_t stream){
  const float* x       = (const float*)d_in[0];
  const int*   adj     = (const int*)d_in[1];
  const float* W_heads = (const float*)d_in[3];
  const float* a_heads = (const float*)d_in[4];
  const float* W_out   = (const float*)d_in[5];
  const float* a_out   = (const float*)d_in[6];
  float* out = (float*)d_out;
  char* ws = (char*)d_ws;

  const size_t MB = 1u << 20;
  const size_t KB = 1u << 10;
  unsigned long long* bitsT = (unsigned long long*)(ws);
  ushort* Wh2T = (ushort*)(ws + 2*MB);
  ushort* Wh1T = (ushort*)(ws + 2*MB + 512*KB);
  ushort* hmat = (ushort*)(ws + 2*MB + 512*KB);
  float*  sR1  = (float*)(ws + 6*MB + 512*KB);
  __fp16* e2p1 = (__fp16*)(ws + 6*MB + 640*KB);
  __fp16* e2n1 = (__fp16*)(ws + 6*MB + 704*KB);
  float*  sR2  = (float*)(ws + 6*MB + 768*KB);
  __fp16* e2p2 = (__fp16*)(ws + 6*MB + 784*KB);
  __fp16* e2n2 = (__fp16*)(ws + 6*MB + 792*KB);
  float*  den1 = (float*)(ws + 7*MB);
  float*  den2 = (float*)(ws + 8*MB);
  float*  num1 = (float*)(ws + 9*MB);
  float*  num2 = num1;

  const int nch1 = (ws_size >= (size_t)41*MB) ? 4 : 2;
  const int nch2 = 16;

  mask_kernel<<<4096, 256, 0, stream>>>(adj, bitsT);
  wh1f_kernel<<<512, 256, 0, stream>>>(x, W_heads, a_heads, Wh1T, sR1, e2p1, e2n1);
  attn_kernel<<<32*8*nch1, 256, 0, stream>>>(Wh1T, bitsT, sR1, e2p1, e2n1,
                                             num1, den1, 8, nch1);
  fin1_kernel<<<2048, 256, 0, stream>>>(num1, den1, hmat, nch1);
  wh2f_kernel<<<512, 256, 0, stream>>>(hmat, W_out, a_out, Wh2T, sR2, e2p2, e2n2);
  attn_kernel<<<32*1*nch2, 256, 0, stream>>>(Wh2T, bitsT, sR2, e2p2, e2n2,
                                             num2, den2, 1, nch2);
  fin2_kernel<<<256, 256, 0, stream>>>(num2, den2, out, nch2);
}

// Round 20
// 99.122 us; speedup vs baseline: 1.2558x; 1.0813x over previous
//
#include <hip/hip_runtime.h>
#include <hip/hip_bf16.h>
#include <cstdint>

#define N 4096
#define L2E 1.44269504088896f

typedef __attribute__((ext_vector_type(2))) __fp16 fp16x2;
typedef __attribute__((ext_vector_type(2))) _Float16 h2f;
typedef __attribute__((ext_vector_type(8))) _Float16 half8;
typedef __attribute__((ext_vector_type(4))) float f32x4;
typedef __attribute__((ext_vector_type(16))) float f32x16;

__device__ __forceinline__ float elu_f(float x){ return x > 0.f ? x : __expf(x) - 1.f; }

// ---- fused pre-pass: blocks 0..511 = layer-1 projection, 512..4607 = mask ----
__global__ __launch_bounds__(256) void pre_kernel(
    const int* __restrict__ adj, unsigned long long* __restrict__ bitsT,
    const float* __restrict__ x, const float* __restrict__ W, const float* __restrict__ a,
    ushort* __restrict__ WhT, float* __restrict__ sR,
    __fp16* __restrict__ e2p, __fp16* __restrict__ e2n){
  __shared__ float xs[8][128];
  int tid = threadIdx.x;
  if (blockIdx.x >= 512){
    // ---------------- mask body ----------------
    int bid = blockIdx.x - 512;
    int gw = (bid * 256 + tid) >> 6;     // 0..16383
    int lane = tid & 63;
    int n = gw >> 2;
    int q = gw & 3;
    const int4* src = (const int4*)(adj + (size_t)n * N + q * 1024);
    unsigned long long words[4];
    #pragma unroll
    for (int it = 0; it < 4; ++it){
      int4 v = src[it*64 + lane];
      unsigned long long nib = (unsigned long long)(
          (v.x != 0 ? 1u : 0u) | (v.y != 0 ? 2u : 0u) |
          (v.z != 0 ? 4u : 0u) | (v.w != 0 ? 8u : 0u));
      unsigned long long xw = nib << ((lane & 15) * 4);
      xw |= __shfl_xor(xw, 1);
      xw |= __shfl_xor(xw, 2);
      xw |= __shfl_xor(xw, 4);
      xw |= __shfl_xor(xw, 8);
      words[it] = xw;
    }
    if ((lane & 15) == 0){
      int k = lane >> 4;
      #pragma unroll
      for (int it = 0; it < 4; ++it){
        int w = q*16 + it*4 + k;
        bitsT[(size_t)w * N + n] = words[it];
      }
    }
    return;
  }
  // ---------------- wh1f body (8-row blocks) ----------------
  int n0 = blockIdx.x * 8;
  {
    const float4* src = (const float4*)(x + (size_t)n0 * 128);
    float4* dst = (float4*)&xs[0][0];
    dst[tid] = src[tid];                 // 8x128 f32 = 256 float4
  }
  __syncthreads();
  int h = tid >> 5;
  int g = tid & 31;
  int o = g * 2;
  const float* Wp = W + h * 8192 + o;
  float acc0[8], acc1[8];
  #pragma unroll
  for (int r = 0; r < 8; ++r){ acc0[r] = 0.f; acc1[r] = 0.f; }
  for (int f4 = 0; f4 < 32; ++f4){
    float2 wv0 = *(const float2*)(Wp + (f4*4+0)*64);
    float2 wv1 = *(const float2*)(Wp + (f4*4+1)*64);
    float2 wv2 = *(const float2*)(Wp + (f4*4+2)*64);
    float2 wv3 = *(const float2*)(Wp + (f4*4+3)*64);
    #pragma unroll
    for (int r = 0; r < 8; ++r){
      float4 xv = *(const float4*)&xs[r][f4*4];
      acc0[r] += xv.x*wv0.x; acc1[r] += xv.x*wv0.y;
      acc0[r] += xv.y*wv1.x; acc1[r] += xv.y*wv1.y;
      acc0[r] += xv.z*wv2.x; acc1[r] += xv.z*wv2.y;
      acc0[r] += xv.w*wv3.x; acc1[r] += xv.w*wv3.y;
    }
  }
  float a1o = a[h*128 + o],      a1o1 = a[h*128 + o + 1];
  float a2o = a[h*128 + 64 + o], a2o1 = a[h*128 + 64 + o + 1];
  float p1[8], p2[8];
  #pragma unroll
  for (int r = 0; r < 8; ++r){
    p1[r] = acc0[r]*a1o + acc1[r]*a1o1;
    p2[r] = acc0[r]*a2o + acc1[r]*a2o1;
  }
  #pragma unroll
  for (int s = 1; s <= 16; s <<= 1){
    #pragma unroll
    for (int r = 0; r < 8; ++r){
      p1[r] += __shfl_xor(p1[r], s);
      p2[r] += __shfl_xor(p2[r], s);
    }
  }
  if (g < 8){
    float f1 = 0.f, f2 = 0.f;
    #pragma unroll
    for (int r = 0; r < 8; ++r){
      f1 = (g == r) ? p1[r] : f1;
      f2 = (g == r) ? p2[r] : f2;
    }
    f1 *= L2E; f2 *= L2E;
    int base = h*N + n0 + g;
    sR[base]  = __builtin_amdgcn_exp2f(-0.8f*f1);
    e2p[base] = (__fp16)__builtin_amdgcn_exp2f(f2);
    e2n[base] = (__fp16)__builtin_amdgcn_exp2f(0.2f*f2);
  }
  union { fp16x2 d[4]; int4 q; } pc0, pc1;
  #pragma unroll
  for (int r = 0; r < 4; ++r){
    pc0.d[r] = __builtin_amdgcn_cvt_pkrtz(acc0[2*r], acc0[2*r+1]);
    pc1.d[r] = __builtin_amdgcn_cvt_pkrtz(acc1[2*r], acc1[2*r+1]);
  }
  ushort* d0 = WhT + ((size_t)(h*64 + o))*N + n0;
  ushort* d1 = WhT + ((size_t)(h*64 + o + 1))*N + n0;
  *(int4*)d0 = pc0.q;
  *(int4*)d1 = pc1.q;
}

// ---------------- fin1: hmat(fp16) = elu(sum num / sum den) ----------------
__global__ __launch_bounds__(256) void fin1_kernel(const float* __restrict__ num,
                                                   const float* __restrict__ den,
                                                   ushort* __restrict__ hmat, int nch){
  int idx4 = blockIdx.x * 256 + threadIdx.x;   // over 8*N*64/4 = 524288 -> 2048 blocks
  int o4 = idx4 & 15;
  int hn = idx4 >> 4;
  int n = hn & (N - 1);
  int h = hn >> 12;
  const f32x4* num4 = (const f32x4*)num;
  f32x4 nu = {};
  float de = 0.f;
  for (int cc = 0; cc < nch; ++cc){
    nu += num4[(size_t)cc*(8*N*16) + (size_t)hn*16 + o4];
    de += den[(size_t)cc*(8*N) + hn];
  }
  float inv = 1.f / de;
  float v0 = elu_f(nu[0]*inv), v1 = elu_f(nu[1]*inv);
  float v2 = elu_f(nu[2]*inv), v3 = elu_f(nu[3]*inv);
  union { fp16x2 d[2]; uint2 q; } pc;
  pc.d[0] = __builtin_amdgcn_cvt_pkrtz(v0, v1);
  pc.d[1] = __builtin_amdgcn_cvt_pkrtz(v2, v3);
  *(uint2*)&hmat[(size_t)n*512 + h*64 + o4*4] = pc.q;
}

// ------- layer-2 projection (8-row blocks) from fp16 hmat ------------------
__global__ __launch_bounds__(256) void wh2f_kernel(
    const ushort* __restrict__ hmat,
    const float* __restrict__ W, const float* __restrict__ a,
    ushort* __restrict__ WhT, float* __restrict__ sR,
    __fp16* __restrict__ e2p, __fp16* __restrict__ e2n){
  __shared__ float hm[8][512];
  int n0 = blockIdx.x * 8;
  int tid = threadIdx.x;
  {
    const uint2* hsrc = (const uint2*)(hmat + (size_t)n0 * 512);   // 1024 uint2
    #pragma unroll
    for (int e = 0; e < 4; ++e){
      int i = tid + e*256;
      union { uint2 q; __fp16 hf[4]; } u;
      u.q = hsrc[i];
      int r = i >> 7;
      int c = (i & 127) * 4;
      hm[r][c]   = (float)u.hf[0];
      hm[r][c+1] = (float)u.hf[1];
      hm[r][c+2] = (float)u.hf[2];
      hm[r][c+3] = (float)u.hf[3];
    }
  }
  __syncthreads();
  int o = tid & 63;
  int rq = tid >> 6;           // 4 groups x 2 rows
  float acc[2] = {0.f, 0.f};
  for (int f4 = 0; f4 < 128; ++f4){
    float w0 = W[(f4*4+0)*64 + o];
    float w1 = W[(f4*4+1)*64 + o];
    float w2 = W[(f4*4+2)*64 + o];
    float w3 = W[(f4*4+3)*64 + o];
    #pragma unroll
    for (int r = 0; r < 2; ++r){
      float4 xv = *(const float4*)&hm[rq*2 + r][f4*4];
      acc[r] += xv.x*w0 + xv.y*w1 + xv.z*w2 + xv.w*w3;
    }
  }
  float a1o = a[o], a2o = a[64 + o];
  float p1[2], p2[2];
  #pragma unroll
  for (int r = 0; r < 2; ++r){ p1[r] = acc[r]*a1o; p2[r] = acc[r]*a2o; }
  #pragma unroll
  for (int s = 1; s <= 32; s <<= 1){
    #pragma unroll
    for (int r = 0; r < 2; ++r){
      p1[r] += __shfl_xor(p1[r], s);
      p2[r] += __shfl_xor(p2[r], s);
    }
  }
  if (o < 2){
    float f1 = 0.f, f2 = 0.f;
    #pragma unroll
    for (int r = 0; r < 2; ++r){
      f1 = (o == r) ? p1[r] : f1;
      f2 = (o == r) ? p2[r] : f2;
    }
    f1 *= L2E; f2 *= L2E;
    int base = n0 + rq*2 + o;
    sR[base]  = __builtin_amdgcn_exp2f(-0.8f*f1);
    e2p[base] = (__fp16)__builtin_amdgcn_exp2f(f2);
    e2n[base] = (__fp16)__builtin_amdgcn_exp2f(0.2f*f2);
  }
  union { fp16x2 d; uint32_t q; } pc;
  pc.d = __builtin_amdgcn_cvt_pkrtz(acc[0], acc[1]);
  ushort* d = WhT + (size_t)o*N + n0 + rq*2;
  *(uint32_t*)d = pc.q;
}

// ---------------- MFMA masked-softmax aggregation (32x32x16 fp16) ----------
// 256 thr (4 waves); 128 n x 64 o per block; wave owns 32 rows.
__global__ __launch_bounds__(256) void attn_kernel(
    const ushort* __restrict__ WhT, const unsigned long long* __restrict__ bitsT,
    const float* __restrict__ sR,
    const __fp16* __restrict__ e2ph, const __fp16* __restrict__ e2nh,
    float* __restrict__ num, float* __restrict__ den, int Hn, int nchunks)
{
  __shared__ ushort Bt[2][4096];          // [64 o][64 m] fp16, swizzled 16B chunks
  __shared__ __fp16 EtP[2][64], EtN[2][64];
  __shared__ uint32_t Mtbl[256][4];       // bb8 -> 4 halfword-mask words
  const int bid  = blockIdx.x;
  const int t    = bid & 31;
  const int rest = bid >> 5;
  const int h    = rest % Hn;
  const int c    = rest / Hn;
  const int n0   = t << 7;                // 128 rows per block
  const int mlen = N / nchunks;
  const int m0b  = c * mlen;
  const int tid  = threadIdx.x;
  const int w    = tid >> 6;
  const int l    = tid & 63;
  const int r32  = l & 31;
  const int kg2  = l >> 5;
  const int n    = n0 + w*32 + r32;

  {
    int i = tid;
    Mtbl[i][0] = ((i&1)  ?0xFFFFu:0u) | ((i&2)  ?0xFFFF0000u:0u);
    Mtbl[i][1] = ((i&4)  ?0xFFFFu:0u) | ((i&8)  ?0xFFFF0000u:0u);
    Mtbl[i][2] = ((i&16) ?0xFFFFu:0u) | ((i&32) ?0xFFFF0000u:0u);
    Mtbl[i][3] = ((i&64) ?0xFFFFu:0u) | ((i&128)?0xFFFF0000u:0u);
  }

  const int hN = h * N;
  union { fp16x2 a; h2f b; } s2u;
  s2u.a = __builtin_amdgcn_cvt_pkrtz(sR[hN + n], sR[hN + n]);
  const h2f s2 = s2u.b;
  const h2f one2 = {(_Float16)1.f, (_Float16)1.f};
  const ushort* Wb = WhT + (size_t)h * 64 * N;

  const int so   = tid >> 3;              // 0..31
  const int slot = tid & 7;
  const int sc   = slot ^ (so & 7);
  const __fp16* evsrc = (((tid & 8) ? e2nh : e2ph) + hN) + ((tid & 7) << 3);

  f32x16 acc0 = {}, acc1 = {};
  float dA[4] = {0.f,0.f,0.f,0.f};

  int4 sv0 = *(const int4*)(Wb + (size_t)so*N      + m0b + sc*8);
  int4 sv1 = *(const int4*)(Wb + (size_t)(so+32)*N + m0b + sc*8);
  int4 evq = {};
  if (tid < 16) evq = *(const int4*)(evsrc + m0b);
  unsigned long long aw = bitsT[(size_t)(m0b >> 6)*N + n];

  #pragma unroll 1
  for (int mt = 0; mt < mlen; mt += 64){
    const int m0 = m0b + mt;
    const int buf = (mt >> 6) & 1;
    const uint32_t awlo = (uint32_t)aw, awhi = (uint32_t)(aw >> 32);
    *(int4*)&Bt[buf][so*64      + slot*8] = sv0;
    *(int4*)&Bt[buf][(so+32)*64 + slot*8] = sv1;
    if (tid < 16)
      *(int4*)(((tid & 8) ? &EtN[buf][0] : &EtP[buf][0]) + ((tid & 7) << 3)) = evq;
    if (mt + 64 < mlen){
      sv0 = *(const int4*)(Wb + (size_t)so*N      + m0 + 64 + sc*8);
      sv1 = *(const int4*)(Wb + (size_t)(so+32)*N + m0 + 64 + sc*8);
      if (tid < 16) evq = *(const int4*)(evsrc + m0 + 64);
      aw = bitsT[(size_t)((m0 + 64) >> 6)*N + n];
    }
    __syncthreads();
    #pragma unroll
    for (int ks = 0; ks < 4; ++ks){
      const int mo = ks*16 + kg2*8;
      union U16x8 { half8 v; h2f p[4]; uint32_t u[4]; } ep, en, wv;
      ep.v = *(const half8*)&EtP[buf][mo];
      en.v = *(const half8*)&EtN[buf][mo];
      const int sh = (ks & 1)*16 + kg2*8;
      const uint32_t bb8 = (((ks < 2) ? awlo : awhi) >> sh) & 0xFFu;
      const uint32_t* mq = &Mtbl[bb8][0];
      #pragma unroll
      for (int p = 0; p < 4; ++p){
        h2f m = __builtin_elementwise_max(ep.p[p], en.p[p] * s2);
        uint32_t mu;
        __builtin_memcpy(&mu, &m, 4);
        mu &= mq[p];
        wv.u[p] = mu;
        h2f hm2;
        __builtin_memcpy(&hm2, &mu, 4);
        dA[p] = __builtin_amdgcn_fdot2(hm2, one2, dA[p], false);
      }
      const int ci = ks*2 + kg2;
      const int sw = (ci ^ (r32 & 7)) << 3;
      half8 B0 = *(const half8*)&Bt[buf][ r32      *64 + sw];
      half8 B1 = *(const half8*)&Bt[buf][(32 + r32)*64 + sw];
      acc0 = __builtin_amdgcn_mfma_f32_32x32x16_f16(wv.v, B0, acc0, 0, 0, 0);
      acc1 = __builtin_amdgcn_mfma_f32_32x32x16_f16(wv.v, B1, acc1, 0, 0, 0);
    }
  }

  const size_t cb = (size_t)(c*Hn + h)*N;
  float* nb = num + (cb + n0 + w*32)*64;
  #pragma unroll
  for (int r = 0; r < 16; ++r){
    int row = (r & 3) + 8*(r >> 2) + 4*kg2;
    nb[(size_t)row*64 +      r32] = acc0[r];
    nb[(size_t)row*64 + 32 + r32] = acc1[r];
  }
  float dacc = (dA[0] + dA[1]) + (dA[2] + dA[3]);
  dacc += __shfl_xor(dacc, 32);
  if (l < 32)
    den[cb + n0 + w*32 + l] = dacc;
}

// ---------------- finalize layer 2: out = elu(sum num / sum den) -----------
__global__ __launch_bounds__(256) void fin2_kernel(const float* __restrict__ num,
                                                   const float* __restrict__ den,
                                                   float* __restrict__ out, int nch){
  int idx4 = blockIdx.x * 256 + threadIdx.x;    // over N*64/4 = 65536
  int n = idx4 >> 4;
  const f32x4* num4 = (const f32x4*)num;
  f32x4 s = {};
  float d = 0.f;
  for (int cc = 0; cc < nch; ++cc){
    s += num4[(size_t)cc*(N*16) + idx4];
    d += den[(size_t)cc*N + n];
  }
  float inv = 1.f / d;
  f32x4 r;
  #pragma unroll
  for (int j = 0; j < 4; ++j) r[j] = elu_f(s[j] * inv);
  *(f32x4*)(out + (size_t)idx4*4) = r;
}

extern "C" void kernel_launch(void* const* d_in, const int* in_sizes, int n_in,
                              void* d_out, int out_size, void* d_ws, size_t ws_size,
                              hipStream_t stream){
  const float* x       = (const float*)d_in[0];
  const int*   adj     = (const int*)d_in[1];
  const float* W_heads = (const float*)d_in[3];
  const float* a_heads = (const float*)d_in[4];
  const float* W_out   = (const float*)d_in[5];
  const float* a_out   = (const float*)d_in[6];
  float* out = (float*)d_out;
  char* ws = (char*)d_ws;

  const size_t MB = 1u << 20;
  const size_t KB = 1u << 10;
  unsigned long long* bitsT = (unsigned long long*)(ws);
  ushort* Wh2T = (ushort*)(ws + 2*MB);
  ushort* Wh1T = (ushort*)(ws + 2*MB + 512*KB);
  ushort* hmat = (ushort*)(ws + 2*MB + 512*KB);
  float*  sR1  = (float*)(ws + 6*MB + 512*KB);
  __fp16* e2p1 = (__fp16*)(ws + 6*MB + 640*KB);
  __fp16* e2n1 = (__fp16*)(ws + 6*MB + 704*KB);
  float*  sR2  = (float*)(ws + 6*MB + 768*KB);
  __fp16* e2p2 = (__fp16*)(ws + 6*MB + 784*KB);
  __fp16* e2n2 = (__fp16*)(ws + 6*MB + 792*KB);
  float*  den1 = (float*)(ws + 7*MB);
  float*  den2 = (float*)(ws + 8*MB);
  float*  num1 = (float*)(ws + 9*MB);
  float*  num2 = num1;

  const int nch1 = (ws_size >= (size_t)41*MB) ? 4 : 2;
  const int nch2 = 16;

  pre_kernel<<<4608, 256, 0, stream>>>(adj, bitsT, x, W_heads, a_heads,
                                       Wh1T, sR1, e2p1, e2n1);
  attn_kernel<<<32*8*nch1, 256, 0, stream>>>(Wh1T, bitsT, sR1, e2p1, e2n1,
                                             num1, den1, 8, nch1);
  fin1_kernel<<<2048, 256, 0, stream>>>(num1, den1, hmat, nch1);
  wh2f_kernel<<<512, 256, 0, stream>>>(hmat, W_out, a_out, Wh2T, sR2, e2p2, e2n2);
  attn_kernel<<<32*1*nch2, 256, 0, stream>>>(Wh2T, bitsT, sR2, e2p2, e2n2,
                                             num2, den2, 1, nch2);
  fin2_kernel<<<256, 256, 0, stream>>>(num2, den2, out, nch2);
}